// Round 1
// baseline (19730.417 us; speedup 1.0000x reference)
//
#include <hip/hip_runtime.h>
#include <math.h>

// Problem dims
#define NB   32      // batch
#define HD   512     // hidden = embed
#define SEQ  64      // source length
#define TSEQ 48      // target length
#define VOC  32000
#define NCHUNK 250   // final gemm N chunks of 128
#define MROWS  1536  // 48*32 decode rows (only first 1504 used for loss)

struct Job {
  const float* bias;                       // [2048]
  const float* x1; const float* W1; int ld1;
  const float* x2; const float* W2; int ld2; const int* idx2;
  const float* x3; const float* W3; int ld3; const int* idx3;
  float* c; float* h; float* hseq;
};
struct Jobs2 { Job j[2]; };

__device__ __forceinline__ float sigmf(float x) { return 1.0f / (1.0f + expf(-x)); }

__global__ __launch_bounds__(256) void zero_kernel(float* p, int n) {
  int i = blockIdx.x * 256 + threadIdx.x;
  if (i < n) p[i] = 0.0f;
}

// Generic LSTM cell step: z[b,n] = bias[n] + sum_i x_i[b,:] . W_i[n,:]
// gates (torch order i,f,g,o at rows n, n+512, n+1024, n+1536), c/h update.
// Thread (b, hq): one hidden index hi = blk*8+hq, 4 gate rows.
// x staged in LDS (shared across the 8 hq slots); weights read direct from
// global (address is uniform across the 32 b-lanes -> coalesces in TA/L1).
__global__ __launch_bounds__(256) void lstm_multi(Jobs2 js) {
  const Job J = js.j[blockIdx.x >> 6];
  const int blk = blockIdx.x & 63;
  const int tid = threadIdx.x;
  const int b = tid & 31;
  const int hq = tid >> 5;
  const int hi = blk * 8 + hq;
  __shared__ __align__(16) float xs[3][32][132];
  float a0 = 0.f, a1 = 0.f, a2 = 0.f, a3 = 0.f;
  const int nin = J.x2 ? (J.x3 ? 3 : 2) : 1;
  for (int k0 = 0; k0 < HD; k0 += 128) {
    for (int i = tid; i < 32 * 128; i += 256) {
      const int bb = i >> 7, kk = i & 127;
      xs[0][bb][kk] = J.x1[(size_t)bb * HD + k0 + kk];
      if (J.x2) {
        const float* r2 = J.idx2 ? J.x2 + (size_t)J.idx2[bb] * HD
                                 : J.x2 + (size_t)bb * HD;
        xs[1][bb][kk] = r2[k0 + kk];
      }
      if (J.x3) {
        const float* r3 = J.idx3 ? J.x3 + (size_t)J.idx3[bb] * HD
                                 : J.x3 + (size_t)bb * HD;
        xs[2][bb][kk] = r3[k0 + kk];
      }
    }
    __syncthreads();
    for (int in = 0; in < nin; ++in) {
      const float* W = (in == 0) ? J.W1 : ((in == 1) ? J.W2 : J.W3);
      const int ld = (in == 0) ? J.ld1 : ((in == 1) ? J.ld2 : J.ld3);
      const float* w0 = W + (size_t)hi * ld + k0;
      const float* w1 = W + (size_t)(hi + 512) * ld + k0;
      const float* w2 = W + (size_t)(hi + 1024) * ld + k0;
      const float* w3 = W + (size_t)(hi + 1536) * ld + k0;
      const float* xr = &xs[in][b][0];
      #pragma unroll 8
      for (int k = 0; k < 128; k += 4) {
        const float4 xv = *(const float4*)(xr + k);
        const float4 wa = *(const float4*)(w0 + k);
        const float4 wb = *(const float4*)(w1 + k);
        const float4 wc = *(const float4*)(w2 + k);
        const float4 wd = *(const float4*)(w3 + k);
        a0 += xv.x * wa.x + xv.y * wa.y + xv.z * wa.z + xv.w * wa.w;
        a1 += xv.x * wb.x + xv.y * wb.y + xv.z * wb.z + xv.w * wb.w;
        a2 += xv.x * wc.x + xv.y * wc.y + xv.z * wc.z + xv.w * wc.w;
        a3 += xv.x * wd.x + xv.y * wd.y + xv.z * wd.z + xv.w * wd.w;
      }
    }
    __syncthreads();
  }
  a0 += J.bias[hi];
  a1 += J.bias[hi + 512];
  a2 += J.bias[hi + 1024];
  a3 += J.bias[hi + 1536];
  const float ig = sigmf(a0), fg = sigmf(a1);
  const float gg = tanhf(a2), og = sigmf(a3);
  const int off = b * HD + hi;
  const float c2 = fg * J.c[off] + ig * gg;
  const float h2 = og * tanhf(c2);
  J.c[off] = c2;
  J.h[off] = h2;
  if (J.hseq) J.hseq[off] = h2;
}

// out[b,hi] = tanh( x1[b,:].W1[hi,:] (+ x2[b,:].W2[hi,:]) ); dual output ptrs
__global__ __launch_bounds__(256) void tanh_proj(
    const float* __restrict__ x1, const float* __restrict__ W1, int ld1,
    const float* __restrict__ x2, const float* __restrict__ W2, int ld2,
    float* __restrict__ out1, float* __restrict__ out2) {
  const int tid = threadIdx.x;
  const int b = tid & 31, hq = tid >> 5;
  const int hi = blockIdx.x * 8 + hq;
  __shared__ __align__(16) float xs[2][32][132];
  float acc = 0.f;
  for (int k0 = 0; k0 < HD; k0 += 128) {
    for (int i = tid; i < 32 * 128; i += 256) {
      const int bb = i >> 7, kk = i & 127;
      xs[0][bb][kk] = x1[(size_t)bb * HD + k0 + kk];
      if (x2) xs[1][bb][kk] = x2[(size_t)bb * HD + k0 + kk];
    }
    __syncthreads();
    {
      const float* wp = W1 + (size_t)hi * ld1 + k0;
      const float* xr = &xs[0][b][0];
      #pragma unroll 8
      for (int k = 0; k < 128; k += 4) {
        const float4 wv = *(const float4*)(wp + k);
        const float4 xv = *(const float4*)(xr + k);
        acc += xv.x * wv.x + xv.y * wv.y + xv.z * wv.z + xv.w * wv.w;
      }
    }
    if (x2) {
      const float* wp = W2 + (size_t)hi * ld2 + k0;
      const float* xr = &xs[1][b][0];
      #pragma unroll 8
      for (int k = 0; k < 128; k += 4) {
        const float4 wv = *(const float4*)(wp + k);
        const float4 xv = *(const float4*)(xr + k);
        acc += xv.x * wv.x + xv.y * wv.y + xv.z * wv.z + xv.w * wv.w;
      }
    }
    __syncthreads();
  }
  const float r = tanhf(acc);
  out1[b * HD + hi] = r;
  if (out2) out2[b * HD + hi] = r;
}

// Per-batch Luong local attention: pt, masked softmax scores, gaussian window, ct
__global__ __launch_bounds__(256) void attn_kernel(
    const float* __restrict__ yt, const float* __restrict__ tanW,
    const float* __restrict__ w2pt, const float* __restrict__ H2,  // [S,B,H]
    const int* __restrict__ elen, float* __restrict__ ct) {
  const int b = blockIdx.x, tid = threadIdx.x;
  __shared__ float yts[512];
  __shared__ float red[256];
  __shared__ float scs[64];
  __shared__ float ats[64];
  __shared__ float ptv, mxs, sms;
  for (int i = tid; i < 512; i += 256) yts[i] = yt[(size_t)b * HD + i];
  float p = 0.f;
  for (int i = tid; i < 512; i += 256) p += tanW[(size_t)b * HD + i] * w2pt[i];
  red[tid] = p;
  __syncthreads();
  for (int s2 = 128; s2 > 0; s2 >>= 1) {
    if (tid < s2) red[tid] += red[tid + s2];
    __syncthreads();
  }
  if (tid == 0) ptv = sigmf(red[0]) * (float)elen[b];
  __syncthreads();
  const int L = elen[b];
  {
    const int s = tid & 63, part = tid >> 6;  // 4 parts x 128 h each
    const float* hrow = H2 + (size_t)s * (NB * HD) + (size_t)b * HD + part * 128;
    const float* xr = &yts[part * 128];
    float sc = 0.f;
    for (int k = 0; k < 128; ++k) sc += xr[k] * hrow[k];
    red[tid] = sc;
  }
  __syncthreads();
  if (tid < 64) {
    const float v = red[tid] + red[tid + 64] + red[tid + 128] + red[tid + 192];
    scs[tid] = (tid < L) ? v : -3.0e38f;
  }
  __syncthreads();
  if (tid == 0) {
    float mx = -3.0e38f;
    for (int i = 0; i < 64; ++i) mx = fmaxf(mx, scs[i]);
    float sm = 0.f;
    for (int i = 0; i < 64; ++i) sm += (i < L) ? expf(scs[i] - mx) : 0.f;
    mxs = mx; sms = sm;
  }
  __syncthreads();
  if (tid < 64) {
    const float al = (tid < L) ? expf(scs[tid] - mxs) / sms : 0.f;
    const float d = (float)tid - ptv;
    ats[tid] = al * expf(-(d * d) * (1.0f / 50.0f));  // denom = D*D/2 = 50
  }
  __syncthreads();
  for (int h = tid; h < 512; h += 256) {
    float acc = 0.f;
    #pragma unroll 8
    for (int s = 0; s < 64; ++s)
      acc += ats[s] * H2[(size_t)s * (NB * HD) + (size_t)b * HD + h];
    ct[b * HD + h] = acc;
  }
}

// Final projection [1536,512] x [512,32000]^T with fused per-block (128 cols)
// logsumexp partials + target-logit capture. 128x128 tile, 8x8 per thread.
__global__ __launch_bounds__(256) void final_gemm(
    const float* __restrict__ A, const float* __restrict__ W,
    const int* __restrict__ target,
    float* __restrict__ pm, float* __restrict__ pl, float* __restrict__ tlg) {
  __shared__ __align__(16) float As[32][132];
  __shared__ __align__(16) float Ws[32][132];
  __shared__ float redm[128][17];
  __shared__ float rowm[128];
  const int tid = threadIdx.x;
  const int tx = tid & 15, ty = tid >> 4;
  const int m0 = blockIdx.y * 128;
  const int n0 = blockIdx.x * 128;
  float acc[8][8];
  #pragma unroll
  for (int i = 0; i < 8; ++i)
    #pragma unroll
    for (int j = 0; j < 8; ++j) acc[i][j] = 0.f;
  for (int k0 = 0; k0 < HD; k0 += 32) {
    for (int i = tid; i < 4096; i += 256) {
      const int m = i >> 5, k = i & 31;
      As[k][m] = A[(size_t)(m0 + m) * HD + k0 + k];
      Ws[k][m] = W[(size_t)(n0 + m) * HD + k0 + k];
    }
    __syncthreads();
    #pragma unroll
    for (int k = 0; k < 32; ++k) {
      const float4 a01 = *(const float4*)&As[k][ty * 8];
      const float4 a23 = *(const float4*)&As[k][ty * 8 + 4];
      const float4 b01 = *(const float4*)&Ws[k][tx * 8];
      const float4 b23 = *(const float4*)&Ws[k][tx * 8 + 4];
      const float av[8] = {a01.x, a01.y, a01.z, a01.w, a23.x, a23.y, a23.z, a23.w};
      const float bv[8] = {b01.x, b01.y, b01.z, b01.w, b23.x, b23.y, b23.z, b23.w};
      #pragma unroll
      for (int i = 0; i < 8; ++i)
        #pragma unroll
        for (int j = 0; j < 8; ++j) acc[i][j] += av[i] * bv[j];
    }
    __syncthreads();
  }
  // per-row max over this block's 128 columns
  #pragma unroll
  for (int i = 0; i < 8; ++i) {
    float m = acc[i][0];
    #pragma unroll
    for (int j = 1; j < 8; ++j) m = fmaxf(m, acc[i][j]);
    redm[ty * 8 + i][tx] = m;
  }
  __syncthreads();
  if (tid < 128) {
    float m2 = redm[tid][0];
    #pragma unroll
    for (int j = 1; j < 16; ++j) m2 = fmaxf(m2, redm[tid][j]);
    rowm[tid] = m2;
  }
  __syncthreads();
  #pragma unroll
  for (int i = 0; i < 8; ++i) {
    const float mm = rowm[ty * 8 + i];
    float s = 0.f;
    #pragma unroll
    for (int j = 0; j < 8; ++j) s += expf(acc[i][j] - mm);
    redm[ty * 8 + i][tx] = s;
  }
  __syncthreads();
  if (tid < 128) {
    float s2 = 0.f;
    #pragma unroll
    for (int j = 0; j < 16; ++j) s2 += redm[tid][j];
    const int row = m0 + tid;
    pm[(size_t)blockIdx.x * MROWS + row] = rowm[tid];
    pl[(size_t)blockIdx.x * MROWS + row] = s2;
  }
  // target-logit capture (exactly one block/thread in the grid matches per row)
  #pragma unroll
  for (int i = 0; i < 8; ++i) {
    const int row = m0 + ty * 8 + i;
    const int t = row >> 5, bb = row & 31;
    if (t < TSEQ - 1) {
      const int tg = target[(t + 1) * NB + bb];
      #pragma unroll
      for (int j = 0; j < 8; ++j) {
        if (n0 + tx * 8 + j == tg) tlg[row] = acc[i][j];
      }
    }
  }
}

// Combine 250 partial (m,l) per row -> lse; lp = tlog - lse (masked); sum over t.
__global__ __launch_bounds__(64) void final_reduce(
    const float* __restrict__ pm, const float* __restrict__ pl,
    const float* __restrict__ tlg, const int* __restrict__ target,
    float* __restrict__ out) {
  const int b = blockIdx.x, tid = threadIdx.x;
  float lp = 0.f;
  if (tid < TSEQ - 1) {
    const int row = tid * NB + b;
    float mx = -3.0e38f;
    for (int i = 0; i < NCHUNK; ++i) mx = fmaxf(mx, pm[(size_t)i * MROWS + row]);
    float l = 0.f;
    for (int i = 0; i < NCHUNK; ++i)
      l += pl[(size_t)i * MROWS + row] * expf(pm[(size_t)i * MROWS + row] - mx);
    const float lse = mx + logf(l);
    const float msk = (target[(tid + 1) * NB + b] != 0) ? 1.f : 0.f;
    lp = (tlg[row] - lse) * msk;
  }
  #pragma unroll
  for (int off = 32; off > 0; off >>= 1) lp += __shfl_down(lp, off);
  if (tid == 0) out[b] = lp;
}

extern "C" void kernel_launch(void* const* d_in, const int* in_sizes, int n_in,
                              void* d_out, int out_size, void* d_ws, size_t ws_size,
                              hipStream_t stream) {
  const int* source = (const int*)d_in[0];
  const int* target = (const int*)d_in[1];
  const int* elen   = (const int*)d_in[2];
  const float* src_emb = (const float*)d_in[3];
  const float* tar_emb = (const float*)d_in[4];
  const float* eW0 = (const float*)d_in[5];
  const float* eU0 = (const float*)d_in[6];
  const float* eb0 = (const float*)d_in[7];
  const float* eW1 = (const float*)d_in[8];
  const float* eU1 = (const float*)d_in[9];
  const float* eb1 = (const float*)d_in[10];
  const float* dW0 = (const float*)d_in[11];   // [2048, 1024]
  const float* dU0 = (const float*)d_in[12];
  const float* db0 = (const float*)d_in[13];
  const float* dW1 = (const float*)d_in[14];
  const float* dU1 = (const float*)d_in[15];
  const float* db1 = (const float*)d_in[16];
  const float* Wht2tan = (const float*)d_in[17];  // [512,512]
  const float* Wtan2pt = (const float*)d_in[18];  // [512]
  const float* Wct2ht  = (const float*)d_in[19];  // [512,1024]
  const float* Wfinal  = (const float*)d_in[20];  // [32000,512]
  float* out = (float*)d_out;

  // Workspace layout (floats)
  float* w = (float*)d_ws;
  float* hA0 = w; w += NB * HD;
  float* hB0 = w; w += NB * HD;
  float* hA1 = w; w += NB * HD;
  float* hB1 = w; w += NB * HD;
  float* c0  = w; w += NB * HD;
  float* c1  = w; w += NB * HD;
  float* dht = w; w += NB * HD;
  float* H1  = w; w += (size_t)SEQ * NB * HD;   // layer-0 outputs [S,B,H]
  float* H2  = w; w += (size_t)SEQ * NB * HD;   // encode_h [S,B,H]
  float* tanW= w; w += NB * HD;
  float* ctb = w; w += NB * HD;
  float* dout= w; w += (size_t)TSEQ * NB * HD;  // [T,B,H]
  float* pm  = w; w += (size_t)NCHUNK * MROWS;
  float* pl  = w; w += (size_t)NCHUNK * MROWS;
  float* tlg = w; w += MROWS;

  // zero initial states (h0/c0/h1/c1/ht) — ws is re-poisoned before every call
  zero_kernel<<<dim3((7 * NB * HD + 255) / 256), dim3(256), 0, stream>>>(hA0, 7 * NB * HD);

  float* h0c = hA0; float* h0n = hB0;
  float* h1c = hA1; float* h1n = hB1;

  // ---------------- encoder: pipelined 2-layer LSTM ----------------
  for (int t = 0; t <= SEQ; ++t) {
    Jobs2 js{}; int nj = 0;
    if (t < SEQ) {                       // layer 0, step t (embed gather fused)
      Job& J = js.j[nj++];
      J.bias = eb0; J.x1 = h0c; J.W1 = eU0; J.ld1 = 512;
      J.x2 = src_emb; J.W2 = eW0; J.ld2 = 512; J.idx2 = source + t * NB;
      J.x3 = nullptr; J.W3 = nullptr; J.ld3 = 0; J.idx3 = nullptr;
      J.c = c0; J.h = h0n; J.hseq = H1 + (size_t)t * NB * HD;
    }
    if (t >= 1) {                        // layer 1, step t-1 (Wih fused as x2)
      Job& J = js.j[nj++];
      J.bias = eb1; J.x1 = h1c; J.W1 = eU1; J.ld1 = 512;
      J.x2 = H1 + (size_t)(t - 1) * NB * HD; J.W2 = eW1; J.ld2 = 512; J.idx2 = nullptr;
      J.x3 = nullptr; J.W3 = nullptr; J.ld3 = 0; J.idx3 = nullptr;
      J.c = c1; J.h = h1n; J.hseq = H2 + (size_t)(t - 1) * NB * HD;
    }
    lstm_multi<<<dim3(64 * nj), dim3(256), 0, stream>>>(js);
    if (t < SEQ) { float* tmp = h0c; h0c = h0n; h0n = tmp; }
    if (t >= 1)  { float* tmp = h1c; h1c = h1n; h1n = tmp; }
  }
  // h0c/c0 = (hn0,cn0), h1c/c1 = (hn1,cn1) -> carried into decoder directly.

  // ---------------- decoder with local attention ----------------
  for (int t = 0; t < TSEQ; ++t) {
    { Jobs2 js{}; Job& J = js.j[0];      // cell0: [y_t, ht] input + recurrent
      J.bias = db0; J.x1 = h0c; J.W1 = dU0; J.ld1 = 512;
      J.x2 = dht; J.W2 = dW0 + 512; J.ld2 = 1024; J.idx2 = nullptr;
      J.x3 = tar_emb; J.W3 = dW0; J.ld3 = 1024; J.idx3 = target + t * NB;
      J.c = c0; J.h = h0n; J.hseq = nullptr;
      lstm_multi<<<dim3(64), dim3(256), 0, stream>>>(js);
    }
    { Jobs2 js{}; Job& J = js.j[0];      // cell1
      J.bias = db1; J.x1 = h1c; J.W1 = dU1; J.ld1 = 512;
      J.x2 = h0n; J.W2 = dW1; J.ld2 = 512; J.idx2 = nullptr;
      J.x3 = nullptr; J.W3 = nullptr; J.ld3 = 0; J.idx3 = nullptr;
      J.c = c1; J.h = h1n; J.hseq = nullptr;
      lstm_multi<<<dim3(64), dim3(256), 0, stream>>>(js);
    }
    tanh_proj<<<dim3(64), dim3(256), 0, stream>>>(
        h1n, Wht2tan, 512, (const float*)nullptr, (const float*)nullptr, 0,
        tanW, (float*)nullptr);
    attn_kernel<<<dim3(32), dim3(256), 0, stream>>>(h1n, tanW, Wtan2pt, H2, elen, ctb);
    tanh_proj<<<dim3(64), dim3(256), 0, stream>>>(
        ctb, Wct2ht, 1024, h1n, Wct2ht + 512, 1024,
        dht, dout + (size_t)t * NB * HD);
    { float* tmp = h0c; h0c = h0n; h0n = tmp; }
    { float* tmp = h1c; h1c = h1n; h1n = tmp; }
  }

  // ---------------- final projection + fused log-softmax ----------------
  final_gemm<<<dim3(NCHUNK, MROWS / 128), dim3(256), 0, stream>>>(
      dout, Wfinal, target, pm, pl, tlg);
  final_reduce<<<dim3(NB), dim3(64), 0, stream>>>(pm, pl, tlg, target, out);

  (void)in_sizes; (void)n_in; (void)out_size; (void)ws_size;
}

// Round 2
// 18405.281 us; speedup vs baseline: 1.0720x; 1.0720x over previous
//
#include <hip/hip_runtime.h>
#include <math.h>

// Problem dims
#define NB   32      // batch
#define HD   512     // hidden = embed
#define SEQ  64      // source length
#define TSEQ 48      // target length
#define NCHUNK 250   // final gemm N chunks of 128
#define MROWS  1536  // 48*32 decode rows (only first 1504 used for loss)
#define XSTR 260     // LDS x-chunk row stride (floats): 256 + pad -> 4-way conflict only
#define MAXSTG 320   // barrier stages: 65 encoder + 240 decoder + slack
#define SCOPE_AG __HIP_MEMORY_SCOPE_AGENT

__device__ __forceinline__ float sigmf(float x) { return 1.0f / (1.0f + expf(-x)); }

__global__ __launch_bounds__(256) void zero_kernel(float* p, int n) {
  int i = blockIdx.x * 256 + threadIdx.x;
  if (i < n) p[i] = 0.0f;
}

// ---- 2-level grid barrier: 8 leaves x 32 blocks -> root. agent-scope. ----
__device__ __forceinline__ void gbar(int* bars, int& stg) {
  __syncthreads();
  if (threadIdx.x == 0) {
    __threadfence();
    int* base = bars + stg * 16;
    int v = __hip_atomic_fetch_add(base + (blockIdx.x & 7), 1, __ATOMIC_ACQ_REL, SCOPE_AG);
    if (v == 31)
      __hip_atomic_fetch_add(base + 8, 1, __ATOMIC_ACQ_REL, SCOPE_AG);
    while (__hip_atomic_load(base + 8, __ATOMIC_ACQUIRE, SCOPE_AG) < 8)
      __builtin_amdgcn_s_sleep(2);
  }
  __syncthreads();
  ++stg;
}

// ---- LSTM cell stage: block covers HPB hidden units (all 4 gates) x 32 b.
// threads = 32 b x (HPB hi x KS k-splits). Each input (K=512) staged to LDS in
// two 256-float chunks; thread dots its k-quarter for its 4 gate rows.
template<int HPB, int KS>
__device__ void cell_stage(int blk,
    const float* x1, const int* i1, const float* W1, int ld1, int co1,
    const float* x2, const int* i2, const float* W2, int ld2, int co2,
    const float* x3, const int* i3, const float* W3, int ld3, int co3,
    const float* bias, float* cbuf, float* hout, float* hseq, float* LDSf) {
  const int tid = threadIdx.x;
  const int b = tid & 31;
  const int q = tid >> 5;
  const int hl = q & (HPB - 1);
  const int ks = q / HPB;
  const int CQ = 256 / KS;
  const int hi = blk * HPB + hl;
  float* xs = LDSf;                 // [32][XSTR]
  float* zp = LDSf + 32 * XSTR;     // [32][33]
  float a0 = 0.f, a1 = 0.f, a2 = 0.f, a3 = 0.f;
  #pragma unroll 1
  for (int in = 0; in < 3; ++in) {
    const float* X = (in == 0) ? x1 : ((in == 1) ? x2 : x3);
    if (!X) break;
    const int* I = (in == 0) ? i1 : ((in == 1) ? i2 : i3);
    const float* W = (in == 0) ? W1 : ((in == 1) ? W2 : W3);
    const int ld = (in == 0) ? ld1 : ((in == 1) ? ld2 : ld3);
    const int co = (in == 0) ? co1 : ((in == 1) ? co2 : co3);
    #pragma unroll 1
    for (int c = 0; c < 2; ++c) {
      for (int j = tid; j < 32 * 64; j += 256) {
        const int bb = j >> 6, f4 = j & 63;
        const float* row = I ? (X + (size_t)I[bb] * HD) : (X + (size_t)bb * HD);
        *(float4*)&xs[bb * XSTR + f4 * 4] = *(const float4*)&row[c * 256 + f4 * 4];
      }
      __syncthreads();
      const int kb = c * 256 + ks * CQ;
      const float* xr = &xs[b * XSTR + ks * CQ];
      const float* w0 = W + (size_t)(hi) * ld + co + kb;
      const float* w1 = W + (size_t)(512 + hi) * ld + co + kb;
      const float* w2 = W + (size_t)(1024 + hi) * ld + co + kb;
      const float* w3 = W + (size_t)(1536 + hi) * ld + co + kb;
      #pragma unroll 4
      for (int k = 0; k < CQ; k += 4) {
        const float4 xv = *(const float4*)(xr + k);
        const float4 wa = *(const float4*)(w0 + k);
        const float4 wb = *(const float4*)(w1 + k);
        const float4 wc = *(const float4*)(w2 + k);
        const float4 wd = *(const float4*)(w3 + k);
        a0 += xv.x * wa.x + xv.y * wa.y + xv.z * wa.z + xv.w * wa.w;
        a1 += xv.x * wb.x + xv.y * wb.y + xv.z * wb.z + xv.w * wb.w;
        a2 += xv.x * wc.x + xv.y * wc.y + xv.z * wc.z + xv.w * wc.w;
        a3 += xv.x * wd.x + xv.y * wd.y + xv.z * wd.z + xv.w * wd.w;
      }
      __syncthreads();
    }
  }
  zp[((hl * 4 + 0) * KS + ks) * 33 + b] = a0;
  zp[((hl * 4 + 1) * KS + ks) * 33 + b] = a1;
  zp[((hl * 4 + 2) * KS + ks) * 33 + b] = a2;
  zp[((hl * 4 + 3) * KS + ks) * 33 + b] = a3;
  __syncthreads();
  if (tid < 32 * HPB) {
    const int b2 = tid & 31, h2 = tid >> 5;
    const int hi2 = blk * HPB + h2;
    float z[4];
    #pragma unroll
    for (int g = 0; g < 4; ++g) {
      float s = bias[g * 512 + hi2];
      #pragma unroll
      for (int k2 = 0; k2 < KS; ++k2) s += zp[((h2 * 4 + g) * KS + k2) * 33 + b2];
      z[g] = s;
    }
    const float ig = sigmf(z[0]), fg = sigmf(z[1]);
    const float gg = tanhf(z[2]), og = sigmf(z[3]);
    const int off = b2 * HD + hi2;
    const float c2 = fg * cbuf[off] + ig * gg;
    const float hv = og * tanhf(c2);
    cbuf[off] = c2;
    hout[off] = hv;
    if (hseq) hseq[off] = hv;
  }
}

// ---- tanh GEMV stage: out[b,r] = tanh(sum_in x_in[b,:].W[r,:]) ----
template<int RPB, int KS>
__device__ void gemv_stage(int blk,
    const float* x1, const float* W1, int ld1, int co1,
    const float* x2, const float* W2, int ld2, int co2,
    float* out1, float* out2, float* LDSf) {
  const int tid = threadIdx.x;
  const int b = tid & 31;
  const int q = tid >> 5;
  const int rl = q & (RPB - 1);
  const int ks = q / RPB;
  const int CQ = 256 / KS;
  const int r = blk * RPB + rl;
  float* xs = LDSf;
  float* zp = LDSf + 32 * XSTR;   // [8][33]
  float acc = 0.f;
  #pragma unroll 1
  for (int in = 0; in < 2; ++in) {
    const float* X = (in == 0) ? x1 : x2;
    if (!X) break;
    const float* W = (in == 0) ? W1 : W2;
    const int ld = (in == 0) ? ld1 : ld2;
    const int co = (in == 0) ? co1 : co2;
    #pragma unroll 1
    for (int c = 0; c < 2; ++c) {
      for (int j = tid; j < 32 * 64; j += 256) {
        const int bb = j >> 6, f4 = j & 63;
        *(float4*)&xs[bb * XSTR + f4 * 4] =
            *(const float4*)&X[(size_t)bb * HD + c * 256 + f4 * 4];
      }
      __syncthreads();
      const int kb = c * 256 + ks * CQ;
      const float* xr = &xs[b * XSTR + ks * CQ];
      const float* wp = W + (size_t)r * ld + co + kb;
      #pragma unroll 4
      for (int k = 0; k < CQ; k += 4) {
        const float4 xv = *(const float4*)(xr + k);
        const float4 wv = *(const float4*)(wp + k);
        acc += xv.x * wv.x + xv.y * wv.y + xv.z * wv.z + xv.w * wv.w;
      }
      __syncthreads();
    }
  }
  zp[(rl * KS + ks) * 33 + b] = acc;
  __syncthreads();
  if (tid < 32 * RPB) {
    const int b2 = tid & 31, rl2 = tid >> 5;
    const int r2 = blk * RPB + rl2;
    float s = 0.f;
    #pragma unroll
    for (int k2 = 0; k2 < KS; ++k2) s += zp[(rl2 * KS + k2) * 33 + b2];
    const float tv = tanhf(s);
    out1[b2 * HD + r2] = tv;
    if (out2) out2[b2 * HD + r2] = tv;
  }
}

// ---- Luong local attention, one block per batch (verified in round 1) ----
__device__ void attn_stage(int b, const float* yt, const float* tanW,
    const float* w2pt, const float* H2, const int* elen, float* ct, float* LDSf) {
  const int tid = threadIdx.x;
  float* yts = LDSf;          // 512
  float* red = LDSf + 512;    // 256
  float* scs = LDSf + 768;    // 64
  float* ats = LDSf + 832;    // 64
  float* sc  = LDSf + 896;    // [0]=pt [1]=max [2]=sum
  for (int i = tid; i < 512; i += 256) yts[i] = yt[(size_t)b * HD + i];
  float p = 0.f;
  for (int i = tid; i < 512; i += 256) p += tanW[(size_t)b * HD + i] * w2pt[i];
  red[tid] = p;
  __syncthreads();
  for (int s2 = 128; s2 > 0; s2 >>= 1) {
    if (tid < s2) red[tid] += red[tid + s2];
    __syncthreads();
  }
  if (tid == 0) sc[0] = sigmf(red[0]) * (float)elen[b];
  __syncthreads();
  const int L = elen[b];
  {
    const int s = tid & 63, part = tid >> 6;
    const float* hrow = H2 + (size_t)s * (NB * HD) + (size_t)b * HD + part * 128;
    const float* xr = &yts[part * 128];
    float s4 = 0.f;
    for (int k = 0; k < 128; ++k) s4 += xr[k] * hrow[k];
    red[tid] = s4;
  }
  __syncthreads();
  if (tid < 64) {
    const float v = red[tid] + red[tid + 64] + red[tid + 128] + red[tid + 192];
    scs[tid] = (tid < L) ? v : -3.0e38f;
  }
  __syncthreads();
  if (tid == 0) {
    float mx = -3.0e38f;
    for (int i = 0; i < 64; ++i) mx = fmaxf(mx, scs[i]);
    float sm = 0.f;
    for (int i = 0; i < 64; ++i) sm += (i < L) ? expf(scs[i] - mx) : 0.f;
    sc[1] = mx; sc[2] = sm;
  }
  __syncthreads();
  if (tid < 64) {
    const float al = (tid < L) ? expf(scs[tid] - sc[1]) / sc[2] : 0.f;
    const float d = (float)tid - sc[0];
    ats[tid] = al * expf(-(d * d) * (1.0f / 50.0f));   // denom = D*D/2 = 50
  }
  __syncthreads();
  for (int h = tid; h < 512; h += 256) {
    float acc = 0.f;
    #pragma unroll 8
    for (int s = 0; s < 64; ++s)
      acc += ats[s] * H2[(size_t)s * (NB * HD) + (size_t)b * HD + h];
    ct[b * HD + h] = acc;
  }
}

struct CoopArgs {
  const int *source, *target, *elen;
  const float *src_emb, *tar_emb;
  const float *eW0, *eU0, *eb0, *eW1, *eU1, *eb1;
  const float *dW0, *dU0, *db0, *dW1, *dU1, *db1;
  const float *Wht2tan, *Wtan2pt, *Wct2ht;
  float *c0, *c1, *h0a, *h0b, *h1a, *h1b, *dht, *tanW, *ct, *H1, *H2, *dout;
  int *bars;
};

// Persistent kernel: full encoder + decoder. 256 blocks x 256 thr, 1 blk/CU.
__global__ __launch_bounds__(256) void coop_kernel(CoopArgs P) {
  __shared__ float LDSf[32 * XSTR + 1100];   // ~37.7 KB
  const int blk = blockIdx.x;
  int stg = 0;
  float* h0buf[2] = {P.h0a, P.h0b};
  float* h1buf[2] = {P.h1a, P.h1b};
  int p0 = 0, p1 = 0;
  // -------- encoder: layer0 (blocks 0-127) + layer1 (128-255) pipelined ----
  for (int t = 0; t <= SEQ; ++t) {
    if (blk < 128) {
      if (t < SEQ)
        cell_stage<4, 2>(blk,
            h0buf[p0], nullptr, P.eU0, 512, 0,
            P.src_emb, P.source + t * NB, P.eW0, 512, 0,
            nullptr, nullptr, nullptr, 0, 0,
            P.eb0, P.c0, h0buf[p0 ^ 1], P.H1 + (size_t)t * NB * HD, LDSf);
    } else {
      if (t >= 1)
        cell_stage<4, 2>(blk - 128,
            h1buf[p1], nullptr, P.eU1, 512, 0,
            P.H1 + (size_t)(t - 1) * NB * HD, nullptr, P.eW1, 512, 0,
            nullptr, nullptr, nullptr, 0, 0,
            P.eb1, P.c1, h1buf[p1 ^ 1], P.H2 + (size_t)(t - 1) * NB * HD, LDSf);
    }
    gbar(P.bars, stg);
    if (t < SEQ) p0 ^= 1;
    if (t >= 1) p1 ^= 1;
  }
  // -------- decoder: 5 stages per step --------
  for (int t = 0; t < TSEQ; ++t) {
    cell_stage<2, 4>(blk,                                // S1: cell0, nin=3
        h0buf[p0], nullptr, P.dU0, 512, 0,
        P.tar_emb, P.target + t * NB, P.dW0, 1024, 0,
        P.dht, nullptr, P.dW0, 1024, 512,
        P.db0, P.c0, h0buf[p0 ^ 1], nullptr, LDSf);
    gbar(P.bars, stg);
    cell_stage<2, 4>(blk,                                // S2: cell1
        h1buf[p1], nullptr, P.dU1, 512, 0,
        h0buf[p0 ^ 1], nullptr, P.dW1, 512, 0,
        nullptr, nullptr, nullptr, 0, 0,
        P.db1, P.c1, h1buf[p1 ^ 1], nullptr, LDSf);
    gbar(P.bars, stg);
    if (blk < 128)                                       // S3: tanh(yt@Wht2tan)
      gemv_stage<4, 2>(blk, h1buf[p1 ^ 1], P.Wht2tan, 512, 0,
                       nullptr, nullptr, 0, 0, P.tanW, nullptr, LDSf);
    gbar(P.bars, stg);
    if (blk < 32)                                        // S4: attention -> ct
      attn_stage(blk, h1buf[p1 ^ 1], P.tanW, P.Wtan2pt, P.H2, P.elen, P.ct, LDSf);
    gbar(P.bars, stg);
    gemv_stage<2, 4>(blk,                                // S5: dht = tanh([ct,yt]W)
        P.ct, P.Wct2ht, 1024, 0,
        h1buf[p1 ^ 1], P.Wct2ht, 1024, 512,
        P.dht, P.dout + (size_t)t * NB * HD, LDSf);
    gbar(P.bars, stg);
    p0 ^= 1; p1 ^= 1;
  }
}

// ---- Final projection [1536,512]x[512,32000]^T, fused per-block logsumexp ----
__global__ __launch_bounds__(256) void final_gemm(
    const float* __restrict__ A, const float* __restrict__ W,
    const int* __restrict__ target,
    float* __restrict__ pm, float* __restrict__ pl, float* __restrict__ tlg) {
  __shared__ __align__(16) float As[32][132];
  __shared__ __align__(16) float Ws[32][132];
  __shared__ float redm[128][17];
  __shared__ float rowm[128];
  const int tid = threadIdx.x;
  const int tx = tid & 15, ty = tid >> 4;
  const int m0 = blockIdx.y * 128;
  const int n0 = blockIdx.x * 128;
  float acc[8][8];
  #pragma unroll
  for (int i = 0; i < 8; ++i)
    #pragma unroll
    for (int j = 0; j < 8; ++j) acc[i][j] = 0.f;
  for (int k0 = 0; k0 < HD; k0 += 32) {
    for (int i = tid; i < 4096; i += 256) {
      const int m = i >> 5, k = i & 31;
      As[k][m] = A[(size_t)(m0 + m) * HD + k0 + k];
      Ws[k][m] = W[(size_t)(n0 + m) * HD + k0 + k];
    }
    __syncthreads();
    #pragma unroll
    for (int k = 0; k < 32; ++k) {
      const float4 a01 = *(const float4*)&As[k][ty * 8];
      const float4 a23 = *(const float4*)&As[k][ty * 8 + 4];
      const float4 b01 = *(const float4*)&Ws[k][tx * 8];
      const float4 b23 = *(const float4*)&Ws[k][tx * 8 + 4];
      const float av[8] = {a01.x, a01.y, a01.z, a01.w, a23.x, a23.y, a23.z, a23.w};
      const float bv[8] = {b01.x, b01.y, b01.z, b01.w, b23.x, b23.y, b23.z, b23.w};
      #pragma unroll
      for (int i = 0; i < 8; ++i)
        #pragma unroll
        for (int j = 0; j < 8; ++j) acc[i][j] += av[i] * bv[j];
    }
    __syncthreads();
  }
  #pragma unroll
  for (int i = 0; i < 8; ++i) {
    float m = acc[i][0];
    #pragma unroll
    for (int j = 1; j < 8; ++j) m = fmaxf(m, acc[i][j]);
    redm[ty * 8 + i][tx] = m;
  }
  __syncthreads();
  if (tid < 128) {
    float m2 = redm[tid][0];
    #pragma unroll
    for (int j = 1; j < 16; ++j) m2 = fmaxf(m2, redm[tid][j]);
    rowm[tid] = m2;
  }
  __syncthreads();
  #pragma unroll
  for (int i = 0; i < 8; ++i) {
    const float mm = rowm[ty * 8 + i];
    float s = 0.f;
    #pragma unroll
    for (int j = 0; j < 8; ++j) s += expf(acc[i][j] - mm);
    redm[ty * 8 + i][tx] = s;
  }
  __syncthreads();
  if (tid < 128) {
    float s2 = 0.f;
    #pragma unroll
    for (int j = 0; j < 16; ++j) s2 += redm[tid][j];
    const int row = m0 + tid;
    pm[(size_t)blockIdx.x * MROWS + row] = rowm[tid];
    pl[(size_t)blockIdx.x * MROWS + row] = s2;
  }
  #pragma unroll
  for (int i = 0; i < 8; ++i) {
    const int row = m0 + ty * 8 + i;
    const int t = row >> 5, bb = row & 31;
    if (t < TSEQ - 1) {
      const int tg = target[(t + 1) * NB + bb];
      #pragma unroll
      for (int j = 0; j < 8; ++j) {
        if (n0 + tx * 8 + j == tg) tlg[row] = acc[i][j];
      }
    }
  }
}

__global__ __launch_bounds__(64) void final_reduce(
    const float* __restrict__ pm, const float* __restrict__ pl,
    const float* __restrict__ tlg, const int* __restrict__ target,
    float* __restrict__ out) {
  const int b = blockIdx.x, tid = threadIdx.x;
  float lp = 0.f;
  if (tid < TSEQ - 1) {
    const int row = tid * NB + b;
    float mx = -3.0e38f;
    for (int i = 0; i < NCHUNK; ++i) mx = fmaxf(mx, pm[(size_t)i * MROWS + row]);
    float l = 0.f;
    for (int i = 0; i < NCHUNK; ++i)
      l += pl[(size_t)i * MROWS + row] * expf(pm[(size_t)i * MROWS + row] - mx);
    const float lse = mx + logf(l);
    const float msk = (target[(tid + 1) * NB + b] != 0) ? 1.f : 0.f;
    lp = (tlg[row] - lse) * msk;
  }
  #pragma unroll
  for (int off = 32; off > 0; off >>= 1) lp += __shfl_down(lp, off);
  if (tid == 0) out[b] = lp;
}

extern "C" void kernel_launch(void* const* d_in, const int* in_sizes, int n_in,
                              void* d_out, int out_size, void* d_ws, size_t ws_size,
                              hipStream_t stream) {
  const int* source = (const int*)d_in[0];
  const int* target = (const int*)d_in[1];
  const int* elen   = (const int*)d_in[2];
  const float* src_emb = (const float*)d_in[3];
  const float* tar_emb = (const float*)d_in[4];
  const float* eW0 = (const float*)d_in[5];
  const float* eU0 = (const float*)d_in[6];
  const float* eb0 = (const float*)d_in[7];
  const float* eW1 = (const float*)d_in[8];
  const float* eU1 = (const float*)d_in[9];
  const float* eb1 = (const float*)d_in[10];
  const float* dW0 = (const float*)d_in[11];   // [2048, 1024]
  const float* dU0 = (const float*)d_in[12];
  const float* db0 = (const float*)d_in[13];
  const float* dW1 = (const float*)d_in[14];
  const float* dU1 = (const float*)d_in[15];
  const float* db1 = (const float*)d_in[16];
  const float* Wht2tan = (const float*)d_in[17];
  const float* Wtan2pt = (const float*)d_in[18];
  const float* Wct2ht  = (const float*)d_in[19];  // [512,1024]
  const float* Wfinal  = (const float*)d_in[20];  // [32000,512]
  float* out = (float*)d_out;

  // Workspace layout. Zero-region first: c0,c1,h0a,h1a,dht + barrier counters.
  float* w = (float*)d_ws;
  float* c0  = w; w += NB * HD;
  float* c1  = w; w += NB * HD;
  float* h0a = w; w += NB * HD;
  float* h1a = w; w += NB * HD;
  float* dht = w; w += NB * HD;
  int* bars = (int*)w; w += MAXSTG * 16;
  float* h0b = w; w += NB * HD;
  float* h1b = w; w += NB * HD;
  float* tanW = w; w += NB * HD;
  float* ct  = w; w += NB * HD;
  float* H1  = w; w += (size_t)SEQ * NB * HD;
  float* H2  = w; w += (size_t)SEQ * NB * HD;
  float* dout = w; w += (size_t)TSEQ * NB * HD;
  float* pm  = w; w += (size_t)NCHUNK * MROWS;
  float* pl  = w; w += (size_t)NCHUNK * MROWS;
  float* tlg = w; w += MROWS;

  const int nzero = 5 * NB * HD + MAXSTG * 16;   // 87040 words
  zero_kernel<<<dim3((nzero + 255) / 256), dim3(256), 0, stream>>>((float*)d_ws, nzero);

  CoopArgs A;
  A.source = source; A.target = target; A.elen = elen;
  A.src_emb = src_emb; A.tar_emb = tar_emb;
  A.eW0 = eW0; A.eU0 = eU0; A.eb0 = eb0;
  A.eW1 = eW1; A.eU1 = eU1; A.eb1 = eb1;
  A.dW0 = dW0; A.dU0 = dU0; A.db0 = db0;
  A.dW1 = dW1; A.dU1 = dU1; A.db1 = db1;
  A.Wht2tan = Wht2tan; A.Wtan2pt = Wtan2pt; A.Wct2ht = Wct2ht;
  A.c0 = c0; A.c1 = c1; A.h0a = h0a; A.h0b = h0b; A.h1a = h1a; A.h1b = h1b;
  A.dht = dht; A.tanW = tanW; A.ct = ct; A.H1 = H1; A.H2 = H2; A.dout = dout;
  A.bars = bars;
  void* kargs[] = {&A};
  hipLaunchCooperativeKernel((void*)coop_kernel, dim3(256), dim3(256), kargs, 0, stream);

  final_gemm<<<dim3(NCHUNK, MROWS / 128), dim3(256), 0, stream>>>(
      dout, Wfinal, target, pm, pl, tlg);
  final_reduce<<<dim3(NB), dim3(64), 0, stream>>>(pm, pl, tlg, target, out);

  (void)in_sizes; (void)n_in; (void)out_size; (void)ws_size;
}

// Round 3
// 14281.294 us; speedup vs baseline: 1.3816x; 1.2888x over previous
//
#include <hip/hip_runtime.h>
#include <math.h>

// Problem dims
#define NB   32      // batch
#define HD   512     // hidden = embed
#define SEQ  64      // source length
#define TSEQ 48      // target length
#define NCHUNK 250   // final gemm N chunks of 128
#define MROWS  1536  // 48*32 decode rows (only first 1504 used for loss)
#define XSTR 260     // LDS x-chunk row stride (floats)
#define MAXSTG 320   // barrier stages: 65 encoder + 240 decoder + slack
#define BARSLOT 32   // ints per barrier counter -> 128 B, own cacheline
#define SCOPE_AG __HIP_MEMORY_SCOPE_AGENT

typedef __bf16 bf16x8 __attribute__((ext_vector_type(8)));
typedef float f32x4 __attribute__((ext_vector_type(4)));

__device__ __forceinline__ float sigmf(float x) { return 1.0f / (1.0f + expf(-x)); }

__global__ __launch_bounds__(256) void zero_kernel(float* p, int n) {
  int i = blockIdx.x * 256 + threadIdx.x;
  if (i < n) p[i] = 0.0f;
}

// ---- 2-level grid barrier, every counter on its OWN cacheline ----
// Round-2 bug: 8 leaves + root shared one 64B line -> 256 serialized
// cross-XCD RMWs -> 53us/barrier. Padding fixes the ping-pong.
__device__ __forceinline__ void gbar(int* bars, int& stg) {
  __syncthreads();
  if (threadIdx.x == 0) {
    int* base = bars + (size_t)stg * 9 * BARSLOT;
    int v = __hip_atomic_fetch_add(base + (blockIdx.x & 7) * BARSLOT, 1,
                                   __ATOMIC_ACQ_REL, SCOPE_AG);
    if (v == 31)
      __hip_atomic_fetch_add(base + 8 * BARSLOT, 1, __ATOMIC_ACQ_REL, SCOPE_AG);
    while (__hip_atomic_load(base + 8 * BARSLOT, __ATOMIC_ACQUIRE, SCOPE_AG) < 8)
      __builtin_amdgcn_s_sleep(4);
  }
  __syncthreads();
  ++stg;
}

// ---- LSTM cell stage (unchanged from round 2, verified correct) ----
template<int HPB, int KS>
__device__ void cell_stage(int blk,
    const float* x1, const int* i1, const float* W1, int ld1, int co1,
    const float* x2, const int* i2, const float* W2, int ld2, int co2,
    const float* x3, const int* i3, const float* W3, int ld3, int co3,
    const float* bias, float* cbuf, float* hout, float* hseq, float* LDSf) {
  const int tid = threadIdx.x;
  const int b = tid & 31;
  const int q = tid >> 5;
  const int hl = q & (HPB - 1);
  const int ks = q / HPB;
  const int CQ = 256 / KS;
  const int hi = blk * HPB + hl;
  float* xs = LDSf;                 // [32][XSTR]
  float* zp = LDSf + 32 * XSTR;     // [32][33]
  float a0 = 0.f, a1 = 0.f, a2 = 0.f, a3 = 0.f;
  #pragma unroll 1
  for (int in = 0; in < 3; ++in) {
    const float* X = (in == 0) ? x1 : ((in == 1) ? x2 : x3);
    if (!X) break;
    const int* I = (in == 0) ? i1 : ((in == 1) ? i2 : i3);
    const float* W = (in == 0) ? W1 : ((in == 1) ? W2 : W3);
    const int ld = (in == 0) ? ld1 : ((in == 1) ? ld2 : ld3);
    const int co = (in == 0) ? co1 : ((in == 1) ? co2 : co3);
    #pragma unroll 1
    for (int c = 0; c < 2; ++c) {
      for (int j = tid; j < 32 * 64; j += 256) {
        const int bb = j >> 6, f4 = j & 63;
        const float* row = I ? (X + (size_t)I[bb] * HD) : (X + (size_t)bb * HD);
        *(float4*)&xs[bb * XSTR + f4 * 4] = *(const float4*)&row[c * 256 + f4 * 4];
      }
      __syncthreads();
      const int kb = c * 256 + ks * CQ;
      const float* xr = &xs[b * XSTR + ks * CQ];
      const float* w0 = W + (size_t)(hi) * ld + co + kb;
      const float* w1 = W + (size_t)(512 + hi) * ld + co + kb;
      const float* w2 = W + (size_t)(1024 + hi) * ld + co + kb;
      const float* w3 = W + (size_t)(1536 + hi) * ld + co + kb;
      #pragma unroll 4
      for (int k = 0; k < CQ; k += 4) {
        const float4 xv = *(const float4*)(xr + k);
        const float4 wa = *(const float4*)(w0 + k);
        const float4 wb = *(const float4*)(w1 + k);
        const float4 wc = *(const float4*)(w2 + k);
        const float4 wd = *(const float4*)(w3 + k);
        a0 += xv.x * wa.x + xv.y * wa.y + xv.z * wa.z + xv.w * wa.w;
        a1 += xv.x * wb.x + xv.y * wb.y + xv.z * wb.z + xv.w * wb.w;
        a2 += xv.x * wc.x + xv.y * wc.y + xv.z * wc.z + xv.w * wc.w;
        a3 += xv.x * wd.x + xv.y * wd.y + xv.z * wd.z + xv.w * wd.w;
      }
      __syncthreads();
    }
  }
  zp[((hl * 4 + 0) * KS + ks) * 33 + b] = a0;
  zp[((hl * 4 + 1) * KS + ks) * 33 + b] = a1;
  zp[((hl * 4 + 2) * KS + ks) * 33 + b] = a2;
  zp[((hl * 4 + 3) * KS + ks) * 33 + b] = a3;
  __syncthreads();
  if (tid < 32 * HPB) {
    const int b2 = tid & 31, h2 = tid >> 5;
    const int hi2 = blk * HPB + h2;
    float z[4];
    #pragma unroll
    for (int g = 0; g < 4; ++g) {
      float s = bias[g * 512 + hi2];
      #pragma unroll
      for (int k2 = 0; k2 < KS; ++k2) s += zp[((h2 * 4 + g) * KS + k2) * 33 + b2];
      z[g] = s;
    }
    const float ig = sigmf(z[0]), fg = sigmf(z[1]);
    const float gg = tanhf(z[2]), og = sigmf(z[3]);
    const int off = b2 * HD + hi2;
    const float c2 = fg * cbuf[off] + ig * gg;
    const float hv = og * tanhf(c2);
    cbuf[off] = c2;
    hout[off] = hv;
    if (hseq) hseq[off] = hv;
  }
}

// ---- tanh GEMV stage (unchanged) ----
template<int RPB, int KS>
__device__ void gemv_stage(int blk,
    const float* x1, const float* W1, int ld1, int co1,
    const float* x2, const float* W2, int ld2, int co2,
    float* out1, float* out2, float* LDSf) {
  const int tid = threadIdx.x;
  const int b = tid & 31;
  const int q = tid >> 5;
  const int rl = q & (RPB - 1);
  const int ks = q / RPB;
  const int CQ = 256 / KS;
  const int r = blk * RPB + rl;
  float* xs = LDSf;
  float* zp = LDSf + 32 * XSTR;
  float acc = 0.f;
  #pragma unroll 1
  for (int in = 0; in < 2; ++in) {
    const float* X = (in == 0) ? x1 : x2;
    if (!X) break;
    const float* W = (in == 0) ? W1 : W2;
    const int ld = (in == 0) ? ld1 : ld2;
    const int co = (in == 0) ? co1 : co2;
    #pragma unroll 1
    for (int c = 0; c < 2; ++c) {
      for (int j = tid; j < 32 * 64; j += 256) {
        const int bb = j >> 6, f4 = j & 63;
        *(float4*)&xs[bb * XSTR + f4 * 4] =
            *(const float4*)&X[(size_t)bb * HD + c * 256 + f4 * 4];
      }
      __syncthreads();
      const int kb = c * 256 + ks * CQ;
      const float* xr = &xs[b * XSTR + ks * CQ];
      const float* wp = W + (size_t)r * ld + co + kb;
      #pragma unroll 4
      for (int k = 0; k < CQ; k += 4) {
        const float4 xv = *(const float4*)(xr + k);
        const float4 wv = *(const float4*)(wp + k);
        acc += xv.x * wv.x + xv.y * wv.y + xv.z * wv.z + xv.w * wv.w;
      }
      __syncthreads();
    }
  }
  zp[(rl * KS + ks) * 33 + b] = acc;
  __syncthreads();
  if (tid < 32 * RPB) {
    const int b2 = tid & 31, rl2 = tid >> 5;
    const int r2 = blk * RPB + rl2;
    float s = 0.f;
    #pragma unroll
    for (int k2 = 0; k2 < KS; ++k2) s += zp[(rl2 * KS + k2) * 33 + b2];
    const float tv = tanhf(s);
    out1[b2 * HD + r2] = tv;
    if (out2) out2[b2 * HD + r2] = tv;
  }
}

// ---- Luong local attention, one block per batch (unchanged) ----
__device__ void attn_stage(int b, const float* yt, const float* tanW,
    const float* w2pt, const float* H2, const int* elen, float* ct, float* LDSf) {
  const int tid = threadIdx.x;
  float* yts = LDSf;
  float* red = LDSf + 512;
  float* scs = LDSf + 768;
  float* ats = LDSf + 832;
  float* sc  = LDSf + 896;
  for (int i = tid; i < 512; i += 256) yts[i] = yt[(size_t)b * HD + i];
  float p = 0.f;
  for (int i = tid; i < 512; i += 256) p += tanW[(size_t)b * HD + i] * w2pt[i];
  red[tid] = p;
  __syncthreads();
  for (int s2 = 128; s2 > 0; s2 >>= 1) {
    if (tid < s2) red[tid] += red[tid + s2];
    __syncthreads();
  }
  if (tid == 0) sc[0] = sigmf(red[0]) * (float)elen[b];
  __syncthreads();
  const int L = elen[b];
  {
    const int s = tid & 63, part = tid >> 6;
    const float* hrow = H2 + (size_t)s * (NB * HD) + (size_t)b * HD + part * 128;
    const float* xr = &yts[part * 128];
    float s4 = 0.f;
    for (int k = 0; k < 128; ++k) s4 += xr[k] * hrow[k];
    red[tid] = s4;
  }
  __syncthreads();
  if (tid < 64) {
    const float v = red[tid] + red[tid + 64] + red[tid + 128] + red[tid + 192];
    scs[tid] = (tid < L) ? v : -3.0e38f;
  }
  __syncthreads();
  if (tid == 0) {
    float mx = -3.0e38f;
    for (int i = 0; i < 64; ++i) mx = fmaxf(mx, scs[i]);
    float sm = 0.f;
    for (int i = 0; i < 64; ++i) sm += (i < L) ? expf(scs[i] - mx) : 0.f;
    sc[1] = mx; sc[2] = sm;
  }
  __syncthreads();
  if (tid < 64) {
    const float al = (tid < L) ? expf(scs[tid] - sc[1]) / sc[2] : 0.f;
    const float d = (float)tid - sc[0];
    ats[tid] = al * expf(-(d * d) * (1.0f / 50.0f));
  }
  __syncthreads();
  for (int h = tid; h < 512; h += 256) {
    float acc = 0.f;
    #pragma unroll 8
    for (int s = 0; s < 64; ++s)
      acc += ats[s] * H2[(size_t)s * (NB * HD) + (size_t)b * HD + h];
    ct[b * HD + h] = acc;
  }
}

struct CoopArgs {
  const int *source, *target, *elen;
  const float *src_emb, *tar_emb;
  const float *eW0, *eU0, *eb0, *eW1, *eU1, *eb1;
  const float *dW0, *dU0, *db0, *dW1, *dU1, *db1;
  const float *Wht2tan, *Wtan2pt, *Wct2ht;
  float *c0, *c1, *h0a, *h0b, *h1a, *h1b, *dht, *tanW, *ct, *H1, *H2, *dout;
  int *bars;
};

__global__ __launch_bounds__(256) void coop_kernel(CoopArgs P) {
  __shared__ float LDSf[32 * XSTR + 1100];
  const int blk = blockIdx.x;
  int stg = 0;
  float* h0buf[2] = {P.h0a, P.h0b};
  float* h1buf[2] = {P.h1a, P.h1b};
  int p0 = 0, p1 = 0;
  for (int t = 0; t <= SEQ; ++t) {
    if (blk < 128) {
      if (t < SEQ)
        cell_stage<4, 2>(blk,
            h0buf[p0], nullptr, P.eU0, 512, 0,
            P.src_emb, P.source + t * NB, P.eW0, 512, 0,
            nullptr, nullptr, nullptr, 0, 0,
            P.eb0, P.c0, h0buf[p0 ^ 1], P.H1 + (size_t)t * NB * HD, LDSf);
    } else {
      if (t >= 1)
        cell_stage<4, 2>(blk - 128,
            h1buf[p1], nullptr, P.eU1, 512, 0,
            P.H1 + (size_t)(t - 1) * NB * HD, nullptr, P.eW1, 512, 0,
            nullptr, nullptr, nullptr, 0, 0,
            P.eb1, P.c1, h1buf[p1 ^ 1], P.H2 + (size_t)(t - 1) * NB * HD, LDSf);
    }
    gbar(P.bars, stg);
    if (t < SEQ) p0 ^= 1;
    if (t >= 1) p1 ^= 1;
  }
  for (int t = 0; t < TSEQ; ++t) {
    cell_stage<2, 4>(blk,
        h0buf[p0], nullptr, P.dU0, 512, 0,
        P.tar_emb, P.target + t * NB, P.dW0, 1024, 0,
        P.dht, nullptr, P.dW0, 1024, 512,
        P.db0, P.c0, h0buf[p0 ^ 1], nullptr, LDSf);
    gbar(P.bars, stg);
    cell_stage<2, 4>(blk,
        h1buf[p1], nullptr, P.dU1, 512, 0,
        h0buf[p0 ^ 1], nullptr, P.dW1, 512, 0,
        nullptr, nullptr, nullptr, 0, 0,
        P.db1, P.c1, h1buf[p1 ^ 1], nullptr, LDSf);
    gbar(P.bars, stg);
    if (blk < 128)
      gemv_stage<4, 2>(blk, h1buf[p1 ^ 1], P.Wht2tan, 512, 0,
                       nullptr, nullptr, 0, 0, P.tanW, nullptr, LDSf);
    gbar(P.bars, stg);
    if (blk < 32)
      attn_stage(blk, h1buf[p1 ^ 1], P.tanW, P.Wtan2pt, P.H2, P.elen, P.ct, LDSf);
    gbar(P.bars, stg);
    gemv_stage<2, 4>(blk,
        P.ct, P.Wct2ht, 1024, 0,
        h1buf[p1 ^ 1], P.Wct2ht, 1024, 512,
        P.dht, P.dout + (size_t)t * NB * HD, LDSf);
    gbar(P.bars, stg);
    p0 ^= 1; p1 ^= 1;
  }
}

// ---- fp32 -> bf16 conversion (RNE) for final projection inputs ----
__device__ __forceinline__ ushort f2bf(float f) {
  unsigned u = __float_as_uint(f);
  u += 0x7fffu + ((u >> 16) & 1u);
  return (ushort)(u >> 16);
}
__global__ __launch_bounds__(256) void cvt_kernel(
    const float* __restrict__ a, ushort* __restrict__ da, int na,
    const float* __restrict__ w, ushort* __restrict__ dw, int nw) {
  int i = (blockIdx.x * 256 + threadIdx.x) * 4;
  if (i < na) {
    float4 v = *(const float4*)(a + i);
    ushort4 o; o.x = f2bf(v.x); o.y = f2bf(v.y); o.z = f2bf(v.z); o.w = f2bf(v.w);
    *(ushort4*)(da + i) = o;
  } else {
    int j = i - na;
    if (j < nw) {
      float4 v = *(const float4*)(w + j);
      ushort4 o; o.x = f2bf(v.x); o.y = f2bf(v.y); o.z = f2bf(v.z); o.w = f2bf(v.w);
      *(ushort4*)(dw + j) = o;
    }
  }
}

// ---- bf16 MFMA final projection: C[1536,32000] tile 64x128/block,
// 4 waves n-split, mfma_f32_16x16x32_bf16, fused per-128-col logsumexp ----
__global__ __launch_bounds__(256) void final_gemm_bf(
    const ushort* __restrict__ Au, const ushort* __restrict__ Wu,
    const int* __restrict__ target,
    float* __restrict__ pm, float* __restrict__ pl, float* __restrict__ tlg) {
  const __bf16* A = (const __bf16*)Au;
  const __bf16* W = (const __bf16*)Wu;
  const int tid = threadIdx.x;
  const int wv = tid >> 6, lane = tid & 63;
  const int l15 = lane & 15, quad = lane >> 4;
  const int m0 = blockIdx.y * 64;
  const int nb = blockIdx.x * 128;
  const int n0 = nb + wv * 32;
  const f32x4 zf = {0.f, 0.f, 0.f, 0.f};
  f32x4 acc[4][2];
  #pragma unroll
  for (int mt = 0; mt < 4; ++mt) { acc[mt][0] = zf; acc[mt][1] = zf; }
  const __bf16* ap  = A + (size_t)(m0 + l15) * HD + quad * 8;
  const __bf16* bp0 = W + (size_t)(n0 + l15) * HD + quad * 8;
  const __bf16* bp1 = W + (size_t)(n0 + 16 + l15) * HD + quad * 8;
  #pragma unroll 2
  for (int k0 = 0; k0 < HD; k0 += 32) {
    const bf16x8 b0 = *(const bf16x8*)(bp0 + k0);
    const bf16x8 b1 = *(const bf16x8*)(bp1 + k0);
    #pragma unroll
    for (int mt = 0; mt < 4; ++mt) {
      const bf16x8 av = *(const bf16x8*)(ap + (size_t)mt * 16 * HD + k0);
      acc[mt][0] = __builtin_amdgcn_mfma_f32_16x16x32_bf16(av, b0, acc[mt][0], 0, 0, 0);
      acc[mt][1] = __builtin_amdgcn_mfma_f32_16x16x32_bf16(av, b1, acc[mt][1], 0, 0, 0);
    }
  }
  // D mapping: row_loc = mt*16 + quad*4 + r, col = n0 + nt*16 + l15
  __shared__ float red[64][5];
  __shared__ float rowm[64];
  #pragma unroll
  for (int mt = 0; mt < 4; ++mt)
    #pragma unroll
    for (int r = 0; r < 4; ++r) {
      float v = fmaxf(acc[mt][0][r], acc[mt][1][r]);
      #pragma unroll
      for (int d = 1; d < 16; d <<= 1) v = fmaxf(v, __shfl_xor(v, d));
      if (l15 == 0) red[mt * 16 + quad * 4 + r][wv] = v;
    }
  __syncthreads();
  if (tid < 64)
    rowm[tid] = fmaxf(fmaxf(red[tid][0], red[tid][1]),
                      fmaxf(red[tid][2], red[tid][3]));
  __syncthreads();
  #pragma unroll
  for (int mt = 0; mt < 4; ++mt)
    #pragma unroll
    for (int r = 0; r < 4; ++r) {
      const float mm = rowm[mt * 16 + quad * 4 + r];
      float s = expf(acc[mt][0][r] - mm) + expf(acc[mt][1][r] - mm);
      #pragma unroll
      for (int d = 1; d < 16; d <<= 1) s += __shfl_xor(s, d);
      if (l15 == 0) red[mt * 16 + quad * 4 + r][wv] = s;
    }
  __syncthreads();
  if (tid < 64) {
    const int row = m0 + tid;
    pm[(size_t)blockIdx.x * MROWS + row] = rowm[tid];
    pl[(size_t)blockIdx.x * MROWS + row] =
        red[tid][0] + red[tid][1] + red[tid][2] + red[tid][3];
  }
  #pragma unroll
  for (int mt = 0; mt < 4; ++mt) {
    const int row = m0 + mt * 16 + quad * 4;
    #pragma unroll
    for (int r = 0; r < 4; ++r) {
      const int t = (row + r) >> 5, bb = (row + r) & 31;
      if (t < TSEQ - 1) {
        const int tg = target[(t + 1) * NB + bb];
        if (n0 + l15 == tg)      tlg[row + r] = acc[mt][0][r];
        if (n0 + 16 + l15 == tg) tlg[row + r] = acc[mt][1][r];
      }
    }
  }
}

__global__ __launch_bounds__(64) void final_reduce(
    const float* __restrict__ pm, const float* __restrict__ pl,
    const float* __restrict__ tlg, const int* __restrict__ target,
    float* __restrict__ out) {
  const int b = blockIdx.x, tid = threadIdx.x;
  float lp = 0.f;
  if (tid < TSEQ - 1) {
    const int row = tid * NB + b;
    float mx = -3.0e38f;
    for (int i = 0; i < NCHUNK; ++i) mx = fmaxf(mx, pm[(size_t)i * MROWS + row]);
    float l = 0.f;
    for (int i = 0; i < NCHUNK; ++i)
      l += pl[(size_t)i * MROWS + row] * expf(pm[(size_t)i * MROWS + row] - mx);
    const float lse = mx + logf(l);
    const float msk = (target[(tid + 1) * NB + b] != 0) ? 1.f : 0.f;
    lp = (tlg[row] - lse) * msk;
  }
  #pragma unroll
  for (int off = 32; off > 0; off >>= 1) lp += __shfl_down(lp, off);
  if (tid == 0) out[b] = lp;
}

extern "C" void kernel_launch(void* const* d_in, const int* in_sizes, int n_in,
                              void* d_out, int out_size, void* d_ws, size_t ws_size,
                              hipStream_t stream) {
  const int* source = (const int*)d_in[0];
  const int* target = (const int*)d_in[1];
  const int* elen   = (const int*)d_in[2];
  const float* src_emb = (const float*)d_in[3];
  const float* tar_emb = (const float*)d_in[4];
  const float* eW0 = (const float*)d_in[5];
  const float* eU0 = (const float*)d_in[6];
  const float* eb0 = (const float*)d_in[7];
  const float* eW1 = (const float*)d_in[8];
  const float* eU1 = (const float*)d_in[9];
  const float* eb1 = (const float*)d_in[10];
  const float* dW0 = (const float*)d_in[11];
  const float* dU0 = (const float*)d_in[12];
  const float* db0 = (const float*)d_in[13];
  const float* dW1 = (const float*)d_in[14];
  const float* dU1 = (const float*)d_in[15];
  const float* db1 = (const float*)d_in[16];
  const float* Wht2tan = (const float*)d_in[17];
  const float* Wtan2pt = (const float*)d_in[18];
  const float* Wct2ht  = (const float*)d_in[19];
  const float* Wfinal  = (const float*)d_in[20];
  float* out = (float*)d_out;

  // Workspace layout. Zero-region first: c0,c1,h0a,h1a,dht + barrier counters.
  float* w = (float*)d_ws;
  float* c0  = w; w += NB * HD;
  float* c1  = w; w += NB * HD;
  float* h0a = w; w += NB * HD;
  float* h1a = w; w += NB * HD;
  float* dht = w; w += NB * HD;
  int* bars = (int*)w; w += MAXSTG * 9 * BARSLOT;
  float* h0b = w; w += NB * HD;
  float* h1b = w; w += NB * HD;
  float* tanW = w; w += NB * HD;
  float* ct  = w; w += NB * HD;
  float* H1  = w; w += (size_t)SEQ * NB * HD;
  float* H2  = w; w += (size_t)SEQ * NB * HD;
  float* dout = w; w += (size_t)TSEQ * NB * HD;
  float* pm  = w; w += (size_t)NCHUNK * MROWS;
  float* pl  = w; w += (size_t)NCHUNK * MROWS;
  float* tlg = w; w += MROWS;
  ushort* Abf = (ushort*)w; w += (MROWS * HD) / 2;            // 1536x512 bf16
  ushort* Wbf = (ushort*)w; w += ((size_t)32000 * HD) / 2;    // 32000x512 bf16

  const int nzero = 5 * NB * HD + MAXSTG * 9 * BARSLOT;
  zero_kernel<<<dim3((nzero + 255) / 256), dim3(256), 0, stream>>>((float*)d_ws, nzero);

  CoopArgs A;
  A.source = source; A.target = target; A.elen = elen;
  A.src_emb = src_emb; A.tar_emb = tar_emb;
  A.eW0 = eW0; A.eU0 = eU0; A.eb0 = eb0;
  A.eW1 = eW1; A.eU1 = eU1; A.eb1 = eb1;
  A.dW0 = dW0; A.dU0 = dU0; A.db0 = db0;
  A.dW1 = dW1; A.dU1 = dU1; A.db1 = db1;
  A.Wht2tan = Wht2tan; A.Wtan2pt = Wtan2pt; A.Wct2ht = Wct2ht;
  A.c0 = c0; A.c1 = c1; A.h0a = h0a; A.h0b = h0b; A.h1a = h1a; A.h1b = h1b;
  A.dht = dht; A.tanW = tanW; A.ct = ct; A.H1 = H1; A.H2 = H2; A.dout = dout;
  A.bars = bars;
  void* kargs[] = {&A};
  hipLaunchCooperativeKernel((void*)coop_kernel, dim3(256), dim3(256), kargs, 0, stream);

  const int na = MROWS * HD;            // 786432
  const int nw = 32000 * HD;            // 16384000
  const int tot4 = (na + nw) / 4;
  cvt_kernel<<<dim3((tot4 + 255) / 256), dim3(256), 0, stream>>>(
      dout, Abf, na, Wfinal, Wbf, nw);
  final_gemm_bf<<<dim3(NCHUNK, MROWS / 64), dim3(256), 0, stream>>>(
      Abf, Wbf, target, pm, pl, tlg);
  final_reduce<<<dim3(NB), dim3(64), 0, stream>>>(pm, pl, tlg, target, out);

  (void)in_sizes; (void)n_in; (void)out_size; (void)ws_size;
}